// Round 8
// baseline (202.541 us; speedup 1.0000x reference)
//
#include <hip/hip_runtime.h>
#include <math.h>

// Problem constants
#define BB   16
#define CC   64
#define DIN  192     // C*K
#define DOUT 128
#define NEXP 8
#define NMAT 9       // 8 routed + 1 shared (fallback path only)
#define NTOK 65536   // B*H*W

#define TOKSTRIDE 200   // LDS bf16 token row stride
#define LOGSTRIDE 9

typedef short bf16x8 __attribute__((ext_vector_type(8)));
typedef float f32x4  __attribute__((ext_vector_type(4)));

// ---- workspace layout (bytes) ----
#define WS_TOK   0u          // bf16[NTOK][192]            25165824
#define WS_WT    25165824u   // bf16[8][128][192] folded   393216 (+pad)
#define WS_TI    25608192u   // float4[NTOK] g0,g1,e0,e1   1048576
#define WS_TOTAL 26656768u

__device__ __forceinline__ unsigned short f2bf(float f) {
    union { float f; unsigned u; } v; v.f = f;
    unsigned u = v.u;
    u += 0x7fffu + ((u >> 16) & 1u);   // RNE (inputs finite)
    return (unsigned short)(u >> 16);
}
__device__ __forceinline__ float bf2f(unsigned short s) {
    union { unsigned u; float f; } v; v.u = ((unsigned)s) << 16;
    return v.f;
}

// ---------------- K1a: conv + router -> tokbuf + tokinfo (unchanged r7) ------
__global__ __launch_bounds__(256)
void k1a_conv(const float* __restrict__ x,
              const float* __restrict__ conv_w,
              const float* __restrict__ router_w,
              const float* __restrict__ w_experts,
              const float* __restrict__ w_shared,
              unsigned short* __restrict__ tokbuf,
              unsigned short* __restrict__ wt,
              float* __restrict__ tokinfo)
{
    __shared__ __attribute__((aligned(16))) unsigned short tokbf[64 * TOKSTRIDE];
    __shared__ float logits[64 * LOGSTRIDE];

    const int tid = threadIdx.x;
    const int bh  = blockIdx.x;          // 1024 = (b,h)
    const int b   = bh >> 6;
    const int h   = bh & 63;

    for (int idx = tid; idx < 64 * LOGSTRIDE; idx += 256) logits[idx] = 0.f;
    __syncthreads();

    // folded-weight transpose slice: wt[e][n][k] = f2bf(We[k][n] + Ws[k][n])
    {
        int idx = bh * 192 + tid;
        if (tid < 192) {
            int e = idx / 24576, rem = idx - e * 24576;
            int n = rem / DIN,  k  = rem - n * DIN;
            wt[idx] = f2bf(w_experts[(size_t)e * 24576 + k * DOUT + n]
                           + w_shared[k * DOUT + n]);
        }
    }

    const int   h0  = (h > 0)  ? (h - 1) : 0;
    const int   h2  = (h < 63) ? (h + 1) : 63;
    const float mh0 = (h > 0)  ? 1.f : 0.f;
    const float mh2 = (h < 63) ? 1.f : 0.f;

    const int w = tid & 63;
    const int q = __builtin_amdgcn_readfirstlane(tid >> 6); // wave-uniform

    const int   wm  = (w == 0)  ? 0  : (w - 1);
    const int   wp  = (w == 63) ? 63 : (w + 1);
    const float mwm = (w == 0)  ? 0.f : 1.f;
    const float mwp = (w == 63) ? 0.f : 1.f;

    float lacc[8];
    #pragma unroll
    for (int e = 0; e < 8; ++e) lacc[e] = 0.f;

    const float* xb = x + (size_t)b * CC * 4096;

    // wave q owns channels q*16 .. q*16+15 (features q*48 .. q*48+47)
    #pragma unroll 2
    for (int i = 0; i < 16; ++i) {
        const int c = q * 16 + i;
        const float* xc = xb + (size_t)c * 4096;
        const float* r0 = xc + h0 * 64;
        const float* r1 = xc + h  * 64;
        const float* r2 = xc + h2 * 64;
        float x00 = r0[wm], x01 = r0[w], x02 = r0[wp];
        float x10 = r1[wm], x11 = r1[w], x12 = r1[wp];
        float x20 = r2[wm], x21 = r2[w], x22 = r2[wp];
        x00 *= mh0 * mwm; x01 *= mh0; x02 *= mh0 * mwp;
        x10 *= mwm;                    x12 *= mwp;
        x20 *= mh2 * mwm; x21 *= mh2; x22 *= mh2 * mwp;

        #pragma unroll
        for (int j = 0; j < 3; ++j) {
            const int f = 3 * c + j;               // wave-uniform
            const float* w9  = conv_w + f * 9;     // scalar loads (L2-hot)
            const float* rwf = router_w + f * 8;   // scalar loads
            float acc = x00 * w9[0] + x01 * w9[1] + x02 * w9[2]
                      + x10 * w9[3] + x11 * w9[4] + x12 * w9[5]
                      + x20 * w9[6] + x21 * w9[7] + x22 * w9[8];
            tokbf[w * TOKSTRIDE + f] = f2bf(acc);
            #pragma unroll
            for (int e = 0; e < 8; ++e) lacc[e] += acc * rwf[e];
        }
    }

    #pragma unroll
    for (int e = 0; e < 8; ++e)
        atomicAdd(&logits[w * LOGSTRIDE + e], lacc[e]);  // 4 threads/(w,e)
    __syncthreads();

    // ---- per-token routing info: top-2, gates ----
    if (tid < 64) {
        float l[8];
        #pragma unroll
        for (int e = 0; e < 8; ++e) l[e] = logits[tid * LOGSTRIDE + e];
        // fp32 exact top-2; strict > keeps lowest index on ties (lax.top_k)
        int e0 = 0; float l0 = l[0];
        #pragma unroll
        for (int e = 1; e < 8; ++e) if (l[e] > l0) { l0 = l[e]; e0 = e; }
        int e1 = -1; float l1 = -INFINITY;
        #pragma unroll
        for (int e = 0; e < 8; ++e) {
            if (e == e0) continue;
            if (l[e] > l1) { l1 = l[e]; e1 = e; }
        }
        float g0 = 1.f / (1.f + expf(l1 - l0));   // softmax Z cancels in renorm
        float4 v;
        v.x = g0; v.y = 1.f - g0;
        v.z = __int_as_float(e0); v.w = __int_as_float(e1);
        *(float4*)(tokinfo + (size_t)(bh * 64 + tid) * 4) = v;
    }

    // tokens LDS -> global (bf16x8 chunks; 64 rows x 24 chunks)
    for (int idx = tid; idx < 1536; idx += 256) {
        int row = idx / 24, seg = idx - row * 24;
        *(bf16x8*)(tokbuf + (size_t)(bh * 64 + row) * 192 + seg * 8) =
            *(const bf16x8*)(tokbf + row * TOKSTRIDE + seg * 8);
    }
}

// ---------------- K2: fused bucketed GEMM + combine + store (r8) -------------
// r8 occupancy fix: r7's k2 measured 87us with LDS 65KB -> 2 blocks/CU,
// Occ 19.9%, HBM 7%, MfmaUtil 4% -- pure latency-bound, no TLP to hide the
// per-tile weight-load chain. The 25.6KB tokbf staging was redundant: each
// block's 64 token rows (24KB) are L2-resident after first touch, so A
// fragments are now gathered DIRECTLY from global tokbuf per tile (64B
// aligned segments). LDS 65 -> ~39.5KB -> 4 blocks/CU, 16 waves/CU (2x TLP).
// Out store vectorized to float4 (16 scalar dwords -> 4x16B per thread).
// RMW scheme + gate!=0 pad-skip identical to r7 (passed correctness).
__global__ __launch_bounds__(256)
void k2_moe(const unsigned short* __restrict__ tokbuf,
            const unsigned short* __restrict__ wt,
            const float* __restrict__ b_experts,
            const float* __restrict__ b_shared,
            const float* __restrict__ tokinfo,
            float* __restrict__ out)
{
    __shared__ float out_lds[64 * 129];            // 33 KB, fp32 accum
    __shared__ float bsum[NEXP * DOUT];            // 4 KB, b_e + b_s
    __shared__ int   rowtok[256];
    __shared__ float rowgate[256];
    __shared__ int   lcnt[8], lstart[8];
    __shared__ int   tilexp[16], tilebase[16];
    __shared__ int   ntiles_s;

    const int tid = threadIdx.x;
    const int bh  = blockIdx.x;            // 1024
    const int b   = bh >> 6;
    const int h   = bh & 63;
    const size_t t0 = (size_t)bh * 64;

    for (int idx = tid; idx < NEXP * DOUT; idx += 256)
        bsum[idx] = b_experts[idx] + b_shared[idx & 127];
    if (tid < 8) lcnt[tid] = 0;
    for (int idx = tid; idx < 64 * 129; idx += 256) out_lds[idx] = 0.f;
    __syncthreads();

    // routing info + local ranks
    int e0 = 0, e1 = 0, r0 = 0, r1 = 0;
    float g0 = 0.f, g1 = 0.f;
    if (tid < 64) {
        float4 ti = *(const float4*)(tokinfo + (t0 + tid) * 4);
        g0 = ti.x; g1 = ti.y;
        e0 = __float_as_int(ti.z); e1 = __float_as_int(ti.w);
        r0 = atomicAdd(&lcnt[e0], 1);
        r1 = atomicAdd(&lcnt[e1], 1);
    }
    __syncthreads();
    if (tid == 0) {
        int start = 0, tb = 0;
        for (int e = 0; e < 8; ++e) {
            lstart[e] = start;
            int tl = (lcnt[e] + 15) >> 4;
            for (int j = 0; j < tl; ++j) {
                tilexp[tb + j] = e; tilebase[tb + j] = start + (j << 4);
            }
            start += tl << 4; tb += tl;
        }
        ntiles_s = tb;
    }
    __syncthreads();
    if (tid < 64) {
        int p0 = lstart[e0] + r0, p1 = lstart[e1] + r1;
        rowtok[p0] = tid; rowgate[p0] = g0;
        rowtok[p1] = tid; rowgate[p1] = g1;
    }
    if (tid < 8) {                       // pad tails: token 0, gate 0 (skipped)
        int e = tid, tl = (lcnt[e] + 15) >> 4;
        for (int j = lcnt[e]; j < (tl << 4); ++j) {
            rowtok[lstart[e] + j] = 0; rowgate[lstart[e] + j] = 0.f;
        }
    }
    __syncthreads();

    // GEMM: wave owns 2 n-blocks (32 out cols); sequential tiles -> safe RMW.
    // A fragments gathered straight from global (block's rows are L2-hot).
    const int wave = tid >> 6, lane = tid & 63;
    const int m16  = lane & 15, quad = lane >> 4;
    const unsigned short* tb_g = tokbuf + t0 * 192;
    const int nt   = ntiles_s;
    for (int ti = 0; ti < nt; ++ti) {
        int e = tilexp[ti], base = tilebase[ti];
        int tA = rowtok[base + m16];
        const unsigned short* ap = tb_g + (size_t)tA * 192 + quad * 8;
        bf16x8 a[6];
        #pragma unroll
        for (int ks = 0; ks < 6; ++ks)
            a[ks] = *(const bf16x8*)(ap + ks * 32);
        int st[4]; float sg[4];
        #pragma unroll
        for (int i = 0; i < 4; ++i) {
            int r = base + quad * 4 + i;
            st[i] = rowtok[r]; sg[i] = rowgate[r];
        }
        const unsigned short* we = wt + (size_t)e * DOUT * DIN;
        #pragma unroll
        for (int nb2 = 0; nb2 < 2; ++nb2) {
            int o = (wave * 2 + nb2) * 16 + m16;
            const unsigned short* wp = we + (size_t)o * DIN + quad * 8;
            f32x4 acc = {0.f, 0.f, 0.f, 0.f};
            #pragma unroll
            for (int ks = 0; ks < 6; ++ks) {
                bf16x8 bfr = *(const bf16x8*)(wp + ks * 32);
                acc = __builtin_amdgcn_mfma_f32_16x16x32_bf16(a[ks], bfr, acc, 0, 0, 0);
            }
            float be = bsum[e * DOUT + o];
            #pragma unroll
            for (int i = 0; i < 4; ++i)
                if (sg[i] != 0.f)              // skip pads (r7 fix)
                    out_lds[st[i] * 129 + o] += sg[i] * (acc[i] + be);
        }
    }
    __syncthreads();

    // float4 transposed store: out[b][o][h][w]; lanes cover 64 w per o
    float* outp = out + ((size_t)b * DOUT) * 4096 + h * 64;
    for (int idx = tid; idx < 2048; idx += 256) {   // 64*128/4
        int o = idx >> 4, wg = (idx & 15) * 4;
        float4 v;
        v.x = out_lds[(wg + 0) * 129 + o];
        v.y = out_lds[(wg + 1) * 129 + o];
        v.z = out_lds[(wg + 2) * 129 + o];
        v.w = out_lds[(wg + 3) * 129 + o];
        *(float4*)(outp + (size_t)o * 4096 + wg) = v;
    }
}

// ================== fallback (round-3 fused path, needs only 442 KB ws) ======
#define OUTSTRIDE 129
#define MAXROWS 320
#define MAXTILES 20

__global__ __launch_bounds__(256)
void moe_conv2d_mfma(const float* __restrict__ x,
                     const float* __restrict__ conv_w,
                     const float* __restrict__ router_w,
                     const unsigned short* __restrict__ wt,
                     const float* __restrict__ b_experts,
                     const float* __restrict__ b_shared,
                     float* __restrict__ out)
{
    __shared__ __attribute__((aligned(16))) unsigned short tokbf[64 * TOKSTRIDE];
    __shared__ float out_lds[64 * OUTSTRIDE];
    __shared__ float rw[DIN * NEXP];
    __shared__ float logits[64 * LOGSTRIDE];
    __shared__ float sg0[64], sg1[64];
    __shared__ int   se0[64], se1[64];
    __shared__ int   rowtok[MAXROWS];
    __shared__ float rowgate[MAXROWS];
    __shared__ int   cbuf[NMAT];
    __shared__ int   tilexp[MAXTILES], tilebase[MAXTILES];
    __shared__ int   ntiles_s;

    const int tid = threadIdx.x;
    const int bh  = blockIdx.x;
    const int b   = bh >> 6;
    const int h   = bh & 63;

    for (int idx = tid; idx < DIN * NEXP; idx += 256) rw[idx] = router_w[idx];
    for (int idx = tid; idx < 64 * LOGSTRIDE; idx += 256) logits[idx] = 0.f;
    __syncthreads();
    {
        const int w  = tid & 63;
        const int fq = tid >> 6;
        float lacc[8];
        #pragma unroll
        for (int e = 0; e < 8; ++e) lacc[e] = 0.f;
        for (int i = 0; i < 48; ++i) {
            int f = i * 4 + fq;
            int c = f / 3;
            const float* wp    = conv_w + f * 9;
            const float* xbase = x + ((size_t)(b * 64 + c) * 64) * 64;
            float acc = 0.f;
            #pragma unroll
            for (int kh = 0; kh < 3; ++kh) {
                int hh = h + kh - 1;
                if (hh < 0 || hh > 63) continue;
                const float* xrow = xbase + hh * 64;
                #pragma unroll
                for (int kw = 0; kw < 3; ++kw) {
                    int ww = w + kw - 1;
                    if (ww < 0 || ww > 63) continue;
                    acc += xrow[ww] * wp[kh * 3 + kw];
                }
            }
            tokbf[w * TOKSTRIDE + f] = f2bf(acc);
            const float* rwf = rw + f * 8;
            #pragma unroll
            for (int e = 0; e < 8; ++e) lacc[e] += acc * rwf[e];
        }
        #pragma unroll
        for (int e = 0; e < 8; ++e)
            atomicAdd(&logits[w * LOGSTRIDE + e], lacc[e]);
    }
    __syncthreads();
    if (tid < 64) {
        int w = tid;
        float l[8];
        #pragma unroll
        for (int e = 0; e < 8; ++e) l[e] = logits[w * LOGSTRIDE + e];
        int e0 = 0; float l0 = l[0];
        #pragma unroll
        for (int e = 1; e < 8; ++e) if (l[e] > l0) { l0 = l[e]; e0 = e; }
        int e1 = -1; float l1 = -INFINITY;
        #pragma unroll
        for (int e = 0; e < 8; ++e) {
            if (e == e0) continue;
            if (l[e] > l1) { l1 = l[e]; e1 = e; }
        }
        float g0 = 1.f / (1.f + expf(l1 - l0));
        sg0[w] = g0; sg1[w] = 1.f - g0;
        se0[w] = e0; se1[w] = e1;
    }
    __syncthreads();
    for (int idx = tid; idx < 64 * DOUT; idx += 256) {
        int t = idx >> 7, o = idx & 127;
        out_lds[t * OUTSTRIDE + o] = b_shared[o]
            + sg0[t] * b_experts[se0[t] * DOUT + o]
            + sg1[t] * b_experts[se1[t] * DOUT + o];
    }
    if (tid < 8) {
        int c = 0;
        for (int t = 0; t < 64; ++t) c += (se0[t] == tid) + (se1[t] == tid);
        cbuf[tid] = c;
    } else if (tid == 8) cbuf[8] = 64;
    __syncthreads();
    if (tid < NMAT) {
        int e = tid;
        int start = 0, tb = 0;
        for (int e2 = 0; e2 < e; ++e2) {
            int ce = cbuf[e2];
            int tl = (ce + 15) >> 4;
            start += tl << 4; tb += tl;
        }
        int ce = cbuf[e];
        int tl = (ce + 15) >> 4;
        for (int j = 0; j < tl; ++j) { tilexp[tb + j] = e; tilebase[tb + j] = start + (j << 4); }
        if (e == 8) ntiles_s = tb + tl;
        int j = 0;
        if (e < 8) {
            for (int t = 0; t < 64; ++t) {
                if (se0[t] == e) { rowtok[start + j] = t; rowgate[start + j] = sg0[t]; ++j; }
                if (se1[t] == e) { rowtok[start + j] = t; rowgate[start + j] = sg1[t]; ++j; }
            }
        } else {
            for (int t = 0; t < 64; ++t) { rowtok[start + j] = t; rowgate[start + j] = 1.f; ++j; }
        }
        for (; j < (tl << 4); ++j) { rowtok[start + j] = 0; rowgate[start + j] = 0.f; }
    }
    __syncthreads();
    {
        const int wave = tid >> 6;
        const int lane = tid & 63;
        const int m16  = lane & 15;
        const int quad = lane >> 4;
        const int nt   = ntiles_s;
        for (int ti = wave; ti < nt; ti += 4) {
            int e    = tilexp[ti];
            int base = tilebase[ti];
            int tA = rowtok[base + m16];
            bf16x8 a[6];
            #pragma unroll
            for (int ks = 0; ks < 6; ++ks)
                a[ks] = *(const bf16x8*)(tokbf + tA * TOKSTRIDE + ks * 32 + quad * 8);
            int st[4]; float sgt[4];
            #pragma unroll
            for (int i2 = 0; i2 < 4; ++i2) {
                int r = base + quad * 4 + i2;
                st[i2] = rowtok[r]; sgt[i2] = rowgate[r];
            }
            const unsigned short* we = wt + (size_t)e * DOUT * DIN;
            for (int n = 0; n < 8; ++n) {
                const unsigned short* wp = we + (size_t)(n * 16 + m16) * DIN + quad * 8;
                f32x4 acc = {0.f, 0.f, 0.f, 0.f};
                #pragma unroll
                for (int ks = 0; ks < 6; ++ks) {
                    bf16x8 bfr2 = *(const bf16x8*)(wp + ks * 32);
                    acc = __builtin_amdgcn_mfma_f32_16x16x32_bf16(a[ks], bfr2, acc, 0, 0, 0);
                }
                int ncol = n * 16 + m16;
                #pragma unroll
                for (int i2 = 0; i2 < 4; ++i2)
                    atomicAdd(&out_lds[st[i2] * OUTSTRIDE + ncol], sgt[i2] * acc[i2]);
            }
        }
    }
    __syncthreads();
    {
        float* outp = out + (((size_t)b * DOUT) * 64 + h) * 64;
        for (int idx = tid; idx < 64 * DOUT; idx += 256) {
            int w = idx & 63, o = idx >> 6;
            outp[(size_t)o * 4096 + w] = out_lds[w * OUTSTRIDE + o];
        }
    }
}

__global__ __launch_bounds__(256)
void prep_weights_only(const float* __restrict__ w_experts,
                       const float* __restrict__ w_shared,
                       unsigned short* __restrict__ wt)
{
    int e = blockIdx.x;
    const float* src = (e < 8) ? (w_experts + (size_t)e * DIN * DOUT) : w_shared;
    unsigned short* dst = wt + (size_t)e * DOUT * DIN;
    for (int idx = threadIdx.x; idx < DOUT * DIN; idx += 256) {
        int n = idx / DIN, k = idx - n * DIN;
        dst[idx] = f2bf(src[k * DOUT + n]);
    }
}

// =============================================================================
extern "C" void kernel_launch(void* const* d_in, const int* in_sizes, int n_in,
                              void* d_out, int out_size, void* d_ws, size_t ws_size,
                              hipStream_t stream)
{
    const float* x         = (const float*)d_in[0];
    const float* conv_w    = (const float*)d_in[1];
    const float* router_w  = (const float*)d_in[2];
    const float* w_experts = (const float*)d_in[3];
    const float* b_experts = (const float*)d_in[4];
    const float* w_shared  = (const float*)d_in[5];
    const float* b_shared  = (const float*)d_in[6];
    float* out = (float*)d_out;
    char* ws = (char*)d_ws;

    if (ws_size >= WS_TOTAL) {
        unsigned short* tokbuf  = (unsigned short*)(ws + WS_TOK);
        unsigned short* wt      = (unsigned short*)(ws + WS_WT);
        float*          tokinfo = (float*)(ws + WS_TI);

        k1a_conv<<<dim3(1024), dim3(256), 0, stream>>>(
            x, conv_w, router_w, w_experts, w_shared, tokbuf, wt, tokinfo);
        k2_moe<<<dim3(1024), dim3(256), 0, stream>>>(
            tokbuf, wt, b_experts, b_shared, tokinfo, out);
    } else {
        // fallback: round-3 fused path (needs only 442 KB ws)
        unsigned short* wt = (unsigned short*)ws;
        prep_weights_only<<<dim3(NMAT), dim3(256), 0, stream>>>(w_experts, w_shared, wt);
        moe_conv2d_mfma<<<dim3(1024), dim3(256), 0, stream>>>(
            x, conv_w, router_w, wt, b_experts, b_shared, out);
    }
}

// Round 9
// 149.427 us; speedup vs baseline: 1.3555x; 1.3555x over previous
//
#include <hip/hip_runtime.h>
#include <math.h>

// Problem constants
#define BB   16
#define CC   64
#define DIN  192     // C*K
#define DOUT 128
#define NEXP 8
#define NMAT 9       // 8 routed + 1 shared (fallback path only)
#define NTOK 65536   // B*H*W
#define CAP  65568   // per-expert bucket capacity
#define SLABROWS 65552  // NTOK + 16 (dump rows for padding)

#define TOKSTRIDE 200   // LDS bf16 token row stride
#define LOGSTRIDE 9
#define CSTRIDE 136     // k4 LDS C-tile stride (shorts)

typedef short bf16x8 __attribute__((ext_vector_type(8)));
typedef float f32x4  __attribute__((ext_vector_type(4)));

// ---- workspace layout (bytes) ----
#define WS_TOK   0u          // bf16[NTOK][192]            25165824
#define WS_WT    25165824u   // bf16[8][128][192] folded   393216 (+pad)
#define WS_CNT   25608192u   // int[16]                    64
#define WS_RT    25608256u   // int[8][CAP] token|slot<<20 2098176
#define WS_RG    27706432u   // float[8][CAP]              2098176
#define WS_SLAB  29804608u   // bf16[2][SLABROWS][128]
#define WS_TOTAL  63367232u  // 2-slab layout

__device__ __forceinline__ unsigned short f2bf(float f) {
    union { float f; unsigned u; } v; v.f = f;
    unsigned u = v.u;
    u += 0x7fffu + ((u >> 16) & 1u);   // RNE (inputs finite)
    return (unsigned short)(u >> 16);
}
__device__ __forceinline__ float bf2f(unsigned short s) {
    union { unsigned u; float f; } v; v.u = ((unsigned)s) << 16;
    return v.f;
}

// ---------------- K1a: conv + router + in-block routing (r5, best measured) --
// r9: full revert to r5's pipeline (148.96us, passed) per r7 kill-rule --
// both fused-k2 variants (r7: 87us LDS-staged, r8: 106us global-A at 2x
// occupancy) proved the per-tile serial chain, not occupancy, is the fused
// design's cost. Shared-expert folding retained: g0+g1=1 =>
// y = g0(A(We0+Ws)+be0+bs) + g1(A(We1+Ws)+be1+bs), exact.
__global__ __launch_bounds__(256)
void k1a_conv(const float* __restrict__ x,
              const float* __restrict__ conv_w,
              const float* __restrict__ router_w,
              const float* __restrict__ w_experts,
              const float* __restrict__ w_shared,
              unsigned short* __restrict__ tokbuf,
              unsigned short* __restrict__ wt,
              int* __restrict__ cnt,
              int* __restrict__ rowtok, float* __restrict__ rowgate)
{
    __shared__ __attribute__((aligned(16))) unsigned short tokbf[64 * TOKSTRIDE];
    __shared__ float logits[64 * LOGSTRIDE];
    __shared__ int lcnt[8];
    __shared__ int lbase[8];

    const int tid = threadIdx.x;
    const int bh  = blockIdx.x;          // 1024 = (b,h)
    const int b   = bh >> 6;
    const int h   = bh & 63;

    for (int idx = tid; idx < 64 * LOGSTRIDE; idx += 256) logits[idx] = 0.f;
    if (tid < 8) lcnt[tid] = 0;
    __syncthreads();

    // folded-weight transpose slice: 192 elems/block (1024*192 = 8*128*192)
    // wt[e][n][k] = f2bf(w_experts[e][k][n] + w_shared[k][n])
    {
        int idx = bh * 192 + tid;
        if (tid < 192) {
            int e = idx / 24576, rem = idx - e * 24576;
            int n = rem / DIN,  k  = rem - n * DIN;
            wt[idx] = f2bf(w_experts[(size_t)e * 24576 + k * DOUT + n]
                           + w_shared[k * DOUT + n]);
        }
    }

    const int   h0  = (h > 0)  ? (h - 1) : 0;
    const int   h2  = (h < 63) ? (h + 1) : 63;
    const float mh0 = (h > 0)  ? 1.f : 0.f;
    const float mh2 = (h < 63) ? 1.f : 0.f;

    const int w = tid & 63;
    const int q = __builtin_amdgcn_readfirstlane(tid >> 6); // wave-uniform

    const int   wm  = (w == 0)  ? 0  : (w - 1);
    const int   wp  = (w == 63) ? 63 : (w + 1);
    const float mwm = (w == 0)  ? 0.f : 1.f;
    const float mwp = (w == 63) ? 0.f : 1.f;

    float lacc[8];
    #pragma unroll
    for (int e = 0; e < 8; ++e) lacc[e] = 0.f;

    const float* xb = x + (size_t)b * CC * 4096;

    // wave q owns channels q*16 .. q*16+15 (features q*48 .. q*48+47)
    #pragma unroll 2
    for (int i = 0; i < 16; ++i) {
        const int c = q * 16 + i;
        const float* xc = xb + (size_t)c * 4096;
        const float* r0 = xc + h0 * 64;
        const float* r1 = xc + h  * 64;
        const float* r2 = xc + h2 * 64;
        float x00 = r0[wm], x01 = r0[w], x02 = r0[wp];
        float x10 = r1[wm], x11 = r1[w], x12 = r1[wp];
        float x20 = r2[wm], x21 = r2[w], x22 = r2[wp];
        x00 *= mh0 * mwm; x01 *= mh0; x02 *= mh0 * mwp;
        x10 *= mwm;                    x12 *= mwp;
        x20 *= mh2 * mwm; x21 *= mh2; x22 *= mh2 * mwp;

        #pragma unroll
        for (int j = 0; j < 3; ++j) {
            const int f = 3 * c + j;               // wave-uniform
            const float* w9  = conv_w + f * 9;     // scalar loads (L2-hot)
            const float* rwf = router_w + f * 8;   // scalar loads
            float acc = x00 * w9[0] + x01 * w9[1] + x02 * w9[2]
                      + x10 * w9[3] + x11 * w9[4] + x12 * w9[5]
                      + x20 * w9[6] + x21 * w9[7] + x22 * w9[8];
            tokbf[w * TOKSTRIDE + f] = f2bf(acc);
            #pragma unroll
            for (int e = 0; e < 8; ++e) lacc[e] += acc * rwf[e];
        }
    }

    #pragma unroll
    for (int e = 0; e < 8; ++e)
        atomicAdd(&logits[w * LOGSTRIDE + e], lacc[e]);  // 4 threads/(w,e)
    __syncthreads();

    // ---- in-block routing: top-2, gates, rank, append ----
    int e0 = 0, e1 = -1, r0k = 0, r1k = 0;
    float g0 = 0.f, g1 = 0.f;
    if (tid < 64) {
        float l[8];
        #pragma unroll
        for (int e = 0; e < 8; ++e) l[e] = logits[tid * LOGSTRIDE + e];
        // fp32 exact top-2; strict > keeps lowest index on ties (lax.top_k)
        float l0 = l[0];
        #pragma unroll
        for (int e = 1; e < 8; ++e) if (l[e] > l0) { l0 = l[e]; e0 = e; }
        float l1 = -INFINITY;
        #pragma unroll
        for (int e = 0; e < 8; ++e) {
            if (e == e0) continue;
            if (l[e] > l1) { l1 = l[e]; e1 = e; }
        }
        g0 = 1.f / (1.f + expf(l1 - l0));   // softmax Z cancels in renorm
        g1 = 1.f - g0;
        r0k = atomicAdd(&lcnt[e0], 1);
        r1k = atomicAdd(&lcnt[e1], 1);
    }
    __syncthreads();
    if (tid < 8) lbase[tid] = atomicAdd(&cnt[tid], lcnt[tid]);
    __syncthreads();
    if (tid < 64) {
        int t   = bh * 64 + tid;
        int p0i = e0 * CAP + lbase[e0] + r0k;
        int p1i = e1 * CAP + lbase[e1] + r1k;
        rowtok[p0i]  = t;
        rowgate[p0i] = g0;
        rowtok[p1i]  = t | (1 << 20);
        rowgate[p1i] = g1;
    }

    // tokens LDS -> global (bf16x8 chunks; 64 rows x 24 chunks)
    for (int idx = tid; idx < 1536; idx += 256) {
        int row = idx / 24, seg = idx - row * 24;
        *(bf16x8*)(tokbuf + (size_t)(bh * 64 + row) * 192 + seg * 8) =
            *(const bf16x8*)(tokbf + row * TOKSTRIDE + seg * 8);
    }
}

// ---------------- K4_all: routed GEMM (shared folded in) -> slot slabs -------
// 2048 blocks: expert e=bid>>8, jb=bid&255, step 256 (bucketed rows).
// wt[e] = (W_e + W_s)^T, bias = b_e + b_s -> slabs sum to the full output.
__global__ __launch_bounds__(256)
void k4_all(const unsigned short* __restrict__ tokbuf,
            const unsigned short* __restrict__ wt,
            const float* __restrict__ b_experts,
            const float* __restrict__ b_shared,
            const int* __restrict__ cnt,
            const int* __restrict__ rowtok, const float* __restrict__ rowgate,
            unsigned short* __restrict__ slab)
{
    __shared__ __attribute__((aligned(16))) unsigned short atile[2][16 * TOKSTRIDE];
    __shared__ __attribute__((aligned(16))) unsigned short ctile[2][16 * CSTRIDE];
    __shared__ int   stok[2][16];
    __shared__ float sgate[2][16];

    const int tid  = threadIdx.x;
    const int e    = blockIdx.x >> 8;
    const int jb   = blockIdx.x & 255;
    const int jstep = 256;

    const int wave = tid >> 6;
    const int lane = tid & 63;
    const int m16  = lane & 15, quad = lane >> 4;
    const int o0   = (wave * 2 + 0) * 16 + m16;
    const int o1   = (wave * 2 + 1) * 16 + m16;

    const unsigned short* wb = wt + (size_t)e * DOUT * DIN;
    bf16x8 bfr0[6], bfr1[6];
    #pragma unroll
    for (int ks = 0; ks < 6; ++ks) {
        bfr0[ks] = *(const bf16x8*)(wb + (size_t)o0 * DIN + ks * 32 + quad * 8);
        bfr1[ks] = *(const bf16x8*)(wb + (size_t)o1 * DIN + ks * 32 + quad * 8);
    }
    const float be0 = b_experts[e * DOUT + o0] + b_shared[o0];
    const float be1 = b_experts[e * DOUT + o1] + b_shared[o1];

    const int cnt_e  = cnt[e];
    const int ntiles = (cnt_e + 15) >> 4;
    const int*   rt = rowtok  + e * CAP;
    const float* rg = rowgate + e * CAP;

    // staging map: idx = tid (+256): row=idx/24, seg=idx%24
    const int r0i = tid / 24,         s0i = tid - r0i * 24;
    const int r1i = (tid + 256) / 24, s1i = (tid + 256) - r1i * 24;
    const bool has1 = (tid + 256) < 384;

    #define FETCH_RAW(r) (((r) < cnt_e) ? rt[r] : NTOK)
    #define FETCH_G(r)   (((r) < cnt_e) ? rg[r] : 0.f)

    // ---- prologue: stage tile jb into buf 0 ----
    if (jb < ntiles) {
        int base = jb * 16;
        if (tid < 16) {
            stok[0][tid]  = FETCH_RAW(base + tid);
            sgate[0][tid] = FETCH_G(base + tid);
        }
        {
            int rawa = FETCH_RAW(base + r0i);
            *(bf16x8*)&atile[0][r0i * TOKSTRIDE + s0i * 8] =
                *(const bf16x8*)(tokbuf + (size_t)(rawa & 0x1FFFF) * 192 + s0i * 8);
            if (has1) {
                int rawb = FETCH_RAW(base + r1i);
                *(bf16x8*)&atile[0][r1i * TOKSTRIDE + s1i * 8] =
                    *(const bf16x8*)(tokbuf + (size_t)(rawb & 0x1FFFF) * 192 + s1i * 8);
            }
        }
    }
    __syncthreads();

    int buf = 0;
    for (int j = jb; j < ntiles; j += jstep, buf ^= 1) {
        const int jn = j + jstep;
        const bool more = (jn < ntiles);

        // ---- issue next tile's global loads into registers (no use yet) ----
        bf16x8 nx0 = {0,0,0,0,0,0,0,0}, nx1 = {0,0,0,0,0,0,0,0};
        int nmt = NTOK; float nmg = 0.f;
        if (more) {
            int base = jn * 16;
            if (tid < 16) { nmt = FETCH_RAW(base + tid); nmg = FETCH_G(base + tid); }
            int rawa = FETCH_RAW(base + r0i);
            nx0 = *(const bf16x8*)(tokbuf + (size_t)(rawa & 0x1FFFF) * 192 + s0i * 8);
            if (has1) {
                int rawb = FETCH_RAW(base + r1i);
                nx1 = *(const bf16x8*)(tokbuf + (size_t)(rawb & 0x1FFFF) * 192 + s1i * 8);
            }
        }

        // ---- compute current tile ----
        bf16x8 a[6];
        #pragma unroll
        for (int ks = 0; ks < 6; ++ks)
            a[ks] = *(const bf16x8*)&atile[buf][m16 * TOKSTRIDE + ks * 32 + quad * 8];

        f32x4 acc0 = {0.f, 0.f, 0.f, 0.f};
        f32x4 acc1 = {0.f, 0.f, 0.f, 0.f};
        #pragma unroll
        for (int ks = 0; ks < 6; ++ks) {
            acc0 = __builtin_amdgcn_mfma_f32_16x16x32_bf16(a[ks], bfr0[ks], acc0, 0, 0, 0);
            acc1 = __builtin_amdgcn_mfma_f32_16x16x32_bf16(a[ks], bfr1[ks], acc1, 0, 0, 0);
        }

        #pragma unroll
        for (int i = 0; i < 4; ++i) {
            int   row = quad * 4 + i;
            float g   = sgate[buf][row];
            ctile[buf][row * CSTRIDE + o0] = f2bf(g * (acc0[i] + be0));
            ctile[buf][row * CSTRIDE + o1] = f2bf(g * (acc1[i] + be1));
        }

        // ---- publish next tile, barrier, wide 16B store ----
        if (more) {
            if (tid < 16) { stok[buf ^ 1][tid] = nmt; sgate[buf ^ 1][tid] = nmg; }
            *(bf16x8*)&atile[buf ^ 1][r0i * TOKSTRIDE + s0i * 8] = nx0;
            if (has1) *(bf16x8*)&atile[buf ^ 1][r1i * TOKSTRIDE + s1i * 8] = nx1;
        }
        __syncthreads();

        {
            int row = tid >> 4, chk = tid & 15;
            int raw = stok[buf][row];
            int t    = raw & 0x1FFFF;
            int slot = raw >> 20;
            *(bf16x8*)(slab + (size_t)slot * SLABROWS * DOUT
                            + (size_t)t * DOUT + chk * 8) =
                *(const bf16x8*)&ctile[buf][row * CSTRIDE + chk * 8];
        }
    }
    #undef FETCH_RAW
    #undef FETCH_G
}

// ---------------- K3_combine: out = slab0 + slab1 ----------------------------
// r9: output store vectorized to float4 (was 16 scalar dwords/thread; G13
// applies to stores too). LDS gather stride 129 == 1 mod 32 -> (4a+b+k)%32
// over 64 lanes = 2 lanes/bank, free (m136).
__global__ __launch_bounds__(256)
void k3_combine(const unsigned short* __restrict__ slab,
                float* __restrict__ out)
{
    __shared__ float out_lds[32 * 129];

    const int tid = threadIdx.x;
    const int bid = blockIdx.x;
    const int bh  = bid >> 1;
    const int wh  = bid & 1;
    const int b   = bh >> 6;
    const int h   = bh & 63;
    const int t0  = bh * 64 + wh * 32;

    const unsigned short* s0 = slab;
    const unsigned short* s1 = slab + (size_t)SLABROWS * DOUT;

    #pragma unroll
    for (int it = 0; it < 2; ++it) {
        int idx = it * 256 + tid;          // 512 = 32 tokens x 16 chunks
        int tl = idx >> 4, chk = idx & 15;
        size_t gt = (size_t)t0 + tl;
        bf16x8 v0 = *(const bf16x8*)(s0 + gt * DOUT + chk * 8);
        bf16x8 v1 = *(const bf16x8*)(s1 + gt * DOUT + chk * 8);
        float* dst = &out_lds[tl * 129 + chk * 8];
        #pragma unroll
        for (int q = 0; q < 8; ++q)
            dst[q] = bf2f((unsigned short)v0[q]) + bf2f((unsigned short)v1[q]);
    }
    __syncthreads();

    // float4 transposed store: 1024 float4 = 128 o-rows x 8 groups of 4 w
    float* outp = out + ((size_t)b * DOUT) * 4096 + h * 64 + wh * 32;
    for (int idx = tid; idx < 1024; idx += 256) {
        int o = idx >> 3, wg = (idx & 7) * 4;
        float4 v;
        v.x = out_lds[(wg + 0) * 129 + o];
        v.y = out_lds[(wg + 1) * 129 + o];
        v.z = out_lds[(wg + 2) * 129 + o];
        v.w = out_lds[(wg + 3) * 129 + o];
        *(float4*)(outp + (size_t)o * 4096 + wg) = v;
    }
}

// ================== fallback (round-3 fused path, needs only 442 KB ws) ======
#define OUTSTRIDE 129
#define MAXROWS 320
#define MAXTILES 20

__global__ __launch_bounds__(256)
void moe_conv2d_mfma(const float* __restrict__ x,
                     const float* __restrict__ conv_w,
                     const float* __restrict__ router_w,
                     const unsigned short* __restrict__ wt,
                     const float* __restrict__ b_experts,
                     const float* __restrict__ b_shared,
                     float* __restrict__ out)
{
    __shared__ __attribute__((aligned(16))) unsigned short tokbf[64 * TOKSTRIDE];
    __shared__ float out_lds[64 * OUTSTRIDE];
    __shared__ float rw[DIN * NEXP];
    __shared__ float logits[64 * LOGSTRIDE];
    __shared__ float sg0[64], sg1[64];
    __shared__ int   se0[64], se1[64];
    __shared__ int   rowtok[MAXROWS];
    __shared__ float rowgate[MAXROWS];
    __shared__ int   cbuf[NMAT];
    __shared__ int   tilexp[MAXTILES], tilebase[MAXTILES];
    __shared__ int   ntiles_s;

    const int tid = threadIdx.x;
    const int bh  = blockIdx.x;
    const int b   = bh >> 6;
    const int h   = bh & 63;

    for (int idx = tid; idx < DIN * NEXP; idx += 256) rw[idx] = router_w[idx];
    for (int idx = tid; idx < 64 * LOGSTRIDE; idx += 256) logits[idx] = 0.f;
    __syncthreads();
    {
        const int w  = tid & 63;
        const int fq = tid >> 6;
        float lacc[8];
        #pragma unroll
        for (int e = 0; e < 8; ++e) lacc[e] = 0.f;
        for (int i = 0; i < 48; ++i) {
            int f = i * 4 + fq;
            int c = f / 3;
            const float* wp    = conv_w + f * 9;
            const float* xbase = x + ((size_t)(b * 64 + c) * 64) * 64;
            float acc = 0.f;
            #pragma unroll
            for (int kh = 0; kh < 3; ++kh) {
                int hh = h + kh - 1;
                if (hh < 0 || hh > 63) continue;
                const float* xrow = xbase + hh * 64;
                #pragma unroll
                for (int kw = 0; kw < 3; ++kw) {
                    int ww = w + kw - 1;
                    if (ww < 0 || ww > 63) continue;
                    acc += xrow[ww] * wp[kh * 3 + kw];
                }
            }
            tokbf[w * TOKSTRIDE + f] = f2bf(acc);
            const float* rwf = rw + f * 8;
            #pragma unroll
            for (int e = 0; e < 8; ++e) lacc[e] += acc * rwf[e];
        }
        #pragma unroll
        for (int e = 0; e < 8; ++e)
            atomicAdd(&logits[w * LOGSTRIDE + e], lacc[e]);
    }
    __syncthreads();
    if (tid < 64) {
        int w = tid;
        float l[8];
        #pragma unroll
        for (int e = 0; e < 8; ++e) l[e] = logits[w * LOGSTRIDE + e];
        int e0 = 0; float l0 = l[0];
        #pragma unroll
        for (int e = 1; e < 8; ++e) if (l[e] > l0) { l0 = l[e]; e0 = e; }
        int e1 = -1; float l1 = -INFINITY;
        #pragma unroll
        for (int e = 0; e < 8; ++e) {
            if (e == e0) continue;
            if (l[e] > l1) { l1 = l[e]; e1 = e; }
        }
        float g0 = 1.f / (1.f + expf(l1 - l0));
        sg0[w] = g0; sg1[w] = 1.f - g0;
        se0[w] = e0; se1[w] = e1;
    }
    __syncthreads();
    for (int idx = tid; idx < 64 * DOUT; idx += 256) {
        int t = idx >> 7, o = idx & 127;
        out_lds[t * OUTSTRIDE + o] = b_shared[o]
            + sg0[t] * b_experts[se0[t] * DOUT + o]
            + sg1[t] * b_experts[se1[t] * DOUT + o];
    }
    if (tid < 8) {
        int c = 0;
        for (int t = 0; t < 64; ++t) c += (se0[t] == tid) + (se1[t] == tid);
        cbuf[tid] = c;
    } else if (tid == 8) cbuf[8] = 64;
    __syncthreads();
    if (tid < NMAT) {
        int e = tid;
        int start = 0, tb = 0;
        for (int e2 = 0; e2 < e; ++e2) {
            int ce = cbuf[e2];
            int tl = (ce + 15) >> 4;
            start += tl << 4; tb += tl;
        }
        int ce = cbuf[e];
        int tl = (ce + 15) >> 4;
        for (int j = 0; j < tl; ++j) { tilexp[tb + j] = e; tilebase[tb + j] = start + (j << 4); }
        if (e == 8) ntiles_s = tb + tl;
        int j = 0;
        if (e < 8) {
            for (int t = 0; t < 64; ++t) {
                if (se0[t] == e) { rowtok[start + j] = t; rowgate[start + j] = sg0[t]; ++j; }
                if (se1[t] == e) { rowtok[start + j] = t; rowgate[start + j] = sg1[t]; ++j; }
            }
        } else {
            for (int t = 0; t < 64; ++t) { rowtok[start + j] = t; rowgate[start + j] = 1.f; ++j; }
        }
        for (; j < (tl << 4); ++j) { rowtok[start + j] = 0; rowgate[start + j] = 0.f; }
    }
    __syncthreads();
    {
        const int wave = tid >> 6;
        const int lane = tid & 63;
        const int m16  = lane & 15;
        const int quad = lane >> 4;
        const int nt   = ntiles_s;
        for (int ti = wave; ti < nt; ti += 4) {
            int e    = tilexp[ti];
            int base = tilebase[ti];
            int tA = rowtok[base + m16];
            bf16x8 a[6];
            #pragma unroll
            for (int ks = 0; ks < 6; ++ks)
                a[ks] = *(const bf16x8*)(tokbf + tA * TOKSTRIDE + ks * 32 + quad * 8);
            int st[4]; float sgt[4];
            #pragma unroll
            for (int i2 = 0; i2 < 4; ++i2) {
                int r = base + quad * 4 + i2;
                st[i2] = rowtok[r]; sgt[i2] = rowgate[r];
            }
            const unsigned short* we = wt + (size_t)e * DOUT * DIN;
            for (int n = 0; n < 8; ++n) {
                const unsigned short* wp = we + (size_t)(n * 16 + m16) * DIN + quad * 8;
                f32x4 acc = {0.f, 0.f, 0.f, 0.f};
                #pragma unroll
                for (int ks = 0; ks < 6; ++ks) {
                    bf16x8 bfr2 = *(const bf16x8*)(wp + ks * 32);
                    acc = __builtin_amdgcn_mfma_f32_16x16x32_bf16(a[ks], bfr2, acc, 0, 0, 0);
                }
                int ncol = n * 16 + m16;
                #pragma unroll
                for (int i2 = 0; i2 < 4; ++i2)
                    atomicAdd(&out_lds[st[i2] * OUTSTRIDE + ncol], sgt[i2] * acc[i2]);
            }
        }
    }
    __syncthreads();
    {
        float* outp = out + (((size_t)b * DOUT) * 64 + h) * 64;
        for (int idx = tid; idx < 64 * DOUT; idx += 256) {
            int w = idx & 63, o = idx >> 6;
            outp[(size_t)o * 4096 + w] = out_lds[w * OUTSTRIDE + o];
        }
    }
}

__global__ __launch_bounds__(256)
void prep_weights_only(const float* __restrict__ w_experts,
                       const float* __restrict__ w_shared,
                       unsigned short* __restrict__ wt)
{
    int e = blockIdx.x;
    const float* src = (e < 8) ? (w_experts + (size_t)e * DIN * DOUT) : w_shared;
    unsigned short* dst = wt + (size_t)e * DOUT * DIN;
    for (int idx = threadIdx.x; idx < DOUT * DIN; idx += 256) {
        int n = idx / DIN, k = idx - n * DIN;
        dst[idx] = f2bf(src[k * DOUT + n]);
    }
}

// =============================================================================
extern "C" void kernel_launch(void* const* d_in, const int* in_sizes, int n_in,
                              void* d_out, int out_size, void* d_ws, size_t ws_size,
                              hipStream_t stream)
{
    const float* x         = (const float*)d_in[0];
    const float* conv_w    = (const float*)d_in[1];
    const float* router_w  = (const float*)d_in[2];
    const float* w_experts = (const float*)d_in[3];
    const float* b_experts = (const float*)d_in[4];
    const float* w_shared  = (const float*)d_in[5];
    const float* b_shared  = (const float*)d_in[6];
    float* out = (float*)d_out;
    char* ws = (char*)d_ws;

    if (ws_size >= WS_TOTAL) {
        unsigned short* tokbuf  = (unsigned short*)(ws + WS_TOK);
        unsigned short* wt      = (unsigned short*)(ws + WS_WT);
        int*            cnt     = (int*)(ws + WS_CNT);
        int*            rowtok  = (int*)(ws + WS_RT);
        float*          rowgate = (float*)(ws + WS_RG);
        unsigned short* slab    = (unsigned short*)(ws + WS_SLAB);

        hipMemsetAsync(cnt, 0, 16 * sizeof(int), stream);   // graph memset node
        k1a_conv<<<dim3(1024), dim3(256), 0, stream>>>(
            x, conv_w, router_w, w_experts, w_shared,
            tokbuf, wt, cnt, rowtok, rowgate);
        k4_all<<<dim3(2048), dim3(256), 0, stream>>>(
            tokbuf, wt, b_experts, b_shared, cnt, rowtok, rowgate, slab);
        k3_combine<<<dim3(2048), dim3(256), 0, stream>>>(slab, out);
    } else {
        // fallback: round-3 fused path (needs only 442 KB ws)
        unsigned short* wt = (unsigned short*)ws;
        prep_weights_only<<<dim3(NMAT), dim3(256), 0, stream>>>(w_experts, w_shared, wt);
        moe_conv2d_mfma<<<dim3(1024), dim3(256), 0, stream>>>(
            x, conv_w, router_w, wt, b_experts, b_shared, out);
    }
}

// Round 10
// 143.616 us; speedup vs baseline: 1.4103x; 1.0405x over previous
//
#include <hip/hip_runtime.h>
#include <math.h>

// Problem constants
#define BB   16
#define CC   64
#define DIN  192     // C*K
#define DOUT 128
#define NEXP 8
#define NMAT 9       // 8 routed + 1 shared (fallback path only)
#define NTOK 65536   // B*H*W
#define CAP  65568   // per-expert bucket capacity
#define SLABROWS 65552  // NTOK + 16 (dump rows for padding)

#define TOKSTRIDE 200   // LDS bf16 token row stride
#define LOGSTRIDE 9
#define CSTRIDE 136     // k4 LDS C-tile stride (shorts)

typedef short bf16x8 __attribute__((ext_vector_type(8)));
typedef float f32x4  __attribute__((ext_vector_type(4)));

// ---- workspace layout (bytes) ----
#define WS_TOK   0u          // bf16[NTOK][192]            25165824
#define WS_WT    25165824u   // bf16[8][128][192] folded   393216 (+pad)
#define WS_CNT   25608192u   // int[16]                    64
#define WS_RT    25608256u   // int[8][CAP] token|slot<<20 2098176
#define WS_RG    27706432u   // float[8][CAP]              2098176
#define WS_SLAB  29804608u   // bf16[2][SLABROWS][128]
#define WS_TOTAL  63367232u  // 2-slab layout

__device__ __forceinline__ unsigned short f2bf(float f) {
    union { float f; unsigned u; } v; v.f = f;
    unsigned u = v.u;
    u += 0x7fffu + ((u >> 16) & 1u);   // RNE (inputs finite)
    return (unsigned short)(u >> 16);
}
__device__ __forceinline__ float bf2f(unsigned short s) {
    union { unsigned u; float f; } v; v.u = ((unsigned)s) << 16;
    return v.f;
}

// ---------------- K1a: conv + router + in-block routing (r5, best measured) --
// Shared-expert folding retained: g0+g1=1 =>
// y = g0(A(We0+Ws)+be0+bs) + g1(A(We1+Ws)+be1+bs), exact.
__global__ __launch_bounds__(256)
void k1a_conv(const float* __restrict__ x,
              const float* __restrict__ conv_w,
              const float* __restrict__ router_w,
              const float* __restrict__ w_experts,
              const float* __restrict__ w_shared,
              unsigned short* __restrict__ tokbuf,
              unsigned short* __restrict__ wt,
              int* __restrict__ cnt,
              int* __restrict__ rowtok, float* __restrict__ rowgate)
{
    __shared__ __attribute__((aligned(16))) unsigned short tokbf[64 * TOKSTRIDE];
    __shared__ float logits[64 * LOGSTRIDE];
    __shared__ int lcnt[8];
    __shared__ int lbase[8];

    const int tid = threadIdx.x;
    const int bh  = blockIdx.x;          // 1024 = (b,h)
    const int b   = bh >> 6;
    const int h   = bh & 63;

    for (int idx = tid; idx < 64 * LOGSTRIDE; idx += 256) logits[idx] = 0.f;
    if (tid < 8) lcnt[tid] = 0;
    __syncthreads();

    // folded-weight transpose slice: 192 elems/block (1024*192 = 8*128*192)
    // wt[e][n][k] = f2bf(w_experts[e][k][n] + w_shared[k][n])
    {
        int idx = bh * 192 + tid;
        if (tid < 192) {
            int e = idx / 24576, rem = idx - e * 24576;
            int n = rem / DIN,  k  = rem - n * DIN;
            wt[idx] = f2bf(w_experts[(size_t)e * 24576 + k * DOUT + n]
                           + w_shared[k * DOUT + n]);
        }
    }

    const int   h0  = (h > 0)  ? (h - 1) : 0;
    const int   h2  = (h < 63) ? (h + 1) : 63;
    const float mh0 = (h > 0)  ? 1.f : 0.f;
    const float mh2 = (h < 63) ? 1.f : 0.f;

    const int w = tid & 63;
    const int q = __builtin_amdgcn_readfirstlane(tid >> 6); // wave-uniform

    const int   wm  = (w == 0)  ? 0  : (w - 1);
    const int   wp  = (w == 63) ? 63 : (w + 1);
    const float mwm = (w == 0)  ? 0.f : 1.f;
    const float mwp = (w == 63) ? 0.f : 1.f;

    float lacc[8];
    #pragma unroll
    for (int e = 0; e < 8; ++e) lacc[e] = 0.f;

    const float* xb = x + (size_t)b * CC * 4096;

    // wave q owns channels q*16 .. q*16+15 (features q*48 .. q*48+47)
    #pragma unroll 2
    for (int i = 0; i < 16; ++i) {
        const int c = q * 16 + i;
        const float* xc = xb + (size_t)c * 4096;
        const float* r0 = xc + h0 * 64;
        const float* r1 = xc + h  * 64;
        const float* r2 = xc + h2 * 64;
        float x00 = r0[wm], x01 = r0[w], x02 = r0[wp];
        float x10 = r1[wm], x11 = r1[w], x12 = r1[wp];
        float x20 = r2[wm], x21 = r2[w], x22 = r2[wp];
        x00 *= mh0 * mwm; x01 *= mh0; x02 *= mh0 * mwp;
        x10 *= mwm;                    x12 *= mwp;
        x20 *= mh2 * mwm; x21 *= mh2; x22 *= mh2 * mwp;

        #pragma unroll
        for (int j = 0; j < 3; ++j) {
            const int f = 3 * c + j;               // wave-uniform
            const float* w9  = conv_w + f * 9;     // scalar loads (L2-hot)
            const float* rwf = router_w + f * 8;   // scalar loads
            float acc = x00 * w9[0] + x01 * w9[1] + x02 * w9[2]
                      + x10 * w9[3] + x11 * w9[4] + x12 * w9[5]
                      + x20 * w9[6] + x21 * w9[7] + x22 * w9[8];
            tokbf[w * TOKSTRIDE + f] = f2bf(acc);
            #pragma unroll
            for (int e = 0; e < 8; ++e) lacc[e] += acc * rwf[e];
        }
    }

    #pragma unroll
    for (int e = 0; e < 8; ++e)
        atomicAdd(&logits[w * LOGSTRIDE + e], lacc[e]);  // 4 threads/(w,e)
    __syncthreads();

    // ---- in-block routing: top-2, gates, rank, append ----
    int e0 = 0, e1 = -1, r0k = 0, r1k = 0;
    float g0 = 0.f, g1 = 0.f;
    if (tid < 64) {
        float l[8];
        #pragma unroll
        for (int e = 0; e < 8; ++e) l[e] = logits[tid * LOGSTRIDE + e];
        // fp32 exact top-2; strict > keeps lowest index on ties (lax.top_k)
        float l0 = l[0];
        #pragma unroll
        for (int e = 1; e < 8; ++e) if (l[e] > l0) { l0 = l[e]; e0 = e; }
        float l1 = -INFINITY;
        #pragma unroll
        for (int e = 0; e < 8; ++e) {
            if (e == e0) continue;
            if (l[e] > l1) { l1 = l[e]; e1 = e; }
        }
        g0 = 1.f / (1.f + expf(l1 - l0));   // softmax Z cancels in renorm
        g1 = 1.f - g0;
        r0k = atomicAdd(&lcnt[e0], 1);
        r1k = atomicAdd(&lcnt[e1], 1);
    }
    __syncthreads();
    if (tid < 8) lbase[tid] = atomicAdd(&cnt[tid], lcnt[tid]);
    __syncthreads();
    if (tid < 64) {
        int t   = bh * 64 + tid;
        int p0i = e0 * CAP + lbase[e0] + r0k;
        int p1i = e1 * CAP + lbase[e1] + r1k;
        rowtok[p0i]  = t;
        rowgate[p0i] = g0;
        rowtok[p1i]  = t | (1 << 20);
        rowgate[p1i] = g1;
    }

    // tokens LDS -> global (bf16x8 chunks; 64 rows x 24 chunks)
    for (int idx = tid; idx < 1536; idx += 256) {
        int row = idx / 24, seg = idx - row * 24;
        *(bf16x8*)(tokbuf + (size_t)(bh * 64 + row) * 192 + seg * 8) =
            *(const bf16x8*)(tokbf + row * TOKSTRIDE + seg * 8);
    }
}

// ---------------- K4_all: routed GEMM (shared folded in) -> slot slabs -------
// r10: 1024 blocks (was 2048): e=bid>>7, jb=bid&127, jstep=128. Per expert
// ~1024 tiles / 128 jb-blocks = ~8 tiles/block (was ~4). The 49 KB/block
// register weight-panel preload (12 bf16x8/thread, ~200cy dependent chain,
// 100 MB aggregate L2 reads at 2048 blocks) is amortized 2x better and the
// double-buffer pipeline spends more iterations in steady state. 4 blocks/CU
// at 21.5 KB LDS -- occupancy unaffected in the proven-working band.
__global__ __launch_bounds__(256)
void k4_all(const unsigned short* __restrict__ tokbuf,
            const unsigned short* __restrict__ wt,
            const float* __restrict__ b_experts,
            const float* __restrict__ b_shared,
            const int* __restrict__ cnt,
            const int* __restrict__ rowtok, const float* __restrict__ rowgate,
            unsigned short* __restrict__ slab)
{
    __shared__ __attribute__((aligned(16))) unsigned short atile[2][16 * TOKSTRIDE];
    __shared__ __attribute__((aligned(16))) unsigned short ctile[2][16 * CSTRIDE];
    __shared__ int   stok[2][16];
    __shared__ float sgate[2][16];

    const int tid  = threadIdx.x;
    const int e    = blockIdx.x >> 7;
    const int jb   = blockIdx.x & 127;
    const int jstep = 128;

    const int wave = tid >> 6;
    const int lane = tid & 63;
    const int m16  = lane & 15, quad = lane >> 4;
    const int o0   = (wave * 2 + 0) * 16 + m16;
    const int o1   = (wave * 2 + 1) * 16 + m16;

    const unsigned short* wb = wt + (size_t)e * DOUT * DIN;
    bf16x8 bfr0[6], bfr1[6];
    #pragma unroll
    for (int ks = 0; ks < 6; ++ks) {
        bfr0[ks] = *(const bf16x8*)(wb + (size_t)o0 * DIN + ks * 32 + quad * 8);
        bfr1[ks] = *(const bf16x8*)(wb + (size_t)o1 * DIN + ks * 32 + quad * 8);
    }
    const float be0 = b_experts[e * DOUT + o0] + b_shared[o0];
    const float be1 = b_experts[e * DOUT + o1] + b_shared[o1];

    const int cnt_e  = cnt[e];
    const int ntiles = (cnt_e + 15) >> 4;
    const int*   rt = rowtok  + e * CAP;
    const float* rg = rowgate + e * CAP;

    // staging map: idx = tid (+256): row=idx/24, seg=idx%24
    const int r0i = tid / 24,         s0i = tid - r0i * 24;
    const int r1i = (tid + 256) / 24, s1i = (tid + 256) - r1i * 24;
    const bool has1 = (tid + 256) < 384;

    #define FETCH_RAW(r) (((r) < cnt_e) ? rt[r] : NTOK)
    #define FETCH_G(r)   (((r) < cnt_e) ? rg[r] : 0.f)

    // ---- prologue: stage tile jb into buf 0 ----
    if (jb < ntiles) {
        int base = jb * 16;
        if (tid < 16) {
            stok[0][tid]  = FETCH_RAW(base + tid);
            sgate[0][tid] = FETCH_G(base + tid);
        }
        {
            int rawa = FETCH_RAW(base + r0i);
            *(bf16x8*)&atile[0][r0i * TOKSTRIDE + s0i * 8] =
                *(const bf16x8*)(tokbuf + (size_t)(rawa & 0x1FFFF) * 192 + s0i * 8);
            if (has1) {
                int rawb = FETCH_RAW(base + r1i);
                *(bf16x8*)&atile[0][r1i * TOKSTRIDE + s1i * 8] =
                    *(const bf16x8*)(tokbuf + (size_t)(rawb & 0x1FFFF) * 192 + s1i * 8);
            }
        }
    }
    __syncthreads();

    int buf = 0;
    for (int j = jb; j < ntiles; j += jstep, buf ^= 1) {
        const int jn = j + jstep;
        const bool more = (jn < ntiles);

        // ---- issue next tile's global loads into registers (no use yet) ----
        bf16x8 nx0 = {0,0,0,0,0,0,0,0}, nx1 = {0,0,0,0,0,0,0,0};
        int nmt = NTOK; float nmg = 0.f;
        if (more) {
            int base = jn * 16;
            if (tid < 16) { nmt = FETCH_RAW(base + tid); nmg = FETCH_G(base + tid); }
            int rawa = FETCH_RAW(base + r0i);
            nx0 = *(const bf16x8*)(tokbuf + (size_t)(rawa & 0x1FFFF) * 192 + s0i * 8);
            if (has1) {
                int rawb = FETCH_RAW(base + r1i);
                nx1 = *(const bf16x8*)(tokbuf + (size_t)(rawb & 0x1FFFF) * 192 + s1i * 8);
            }
        }

        // ---- compute current tile ----
        bf16x8 a[6];
        #pragma unroll
        for (int ks = 0; ks < 6; ++ks)
            a[ks] = *(const bf16x8*)&atile[buf][m16 * TOKSTRIDE + ks * 32 + quad * 8];

        f32x4 acc0 = {0.f, 0.f, 0.f, 0.f};
        f32x4 acc1 = {0.f, 0.f, 0.f, 0.f};
        #pragma unroll
        for (int ks = 0; ks < 6; ++ks) {
            acc0 = __builtin_amdgcn_mfma_f32_16x16x32_bf16(a[ks], bfr0[ks], acc0, 0, 0, 0);
            acc1 = __builtin_amdgcn_mfma_f32_16x16x32_bf16(a[ks], bfr1[ks], acc1, 0, 0, 0);
        }

        #pragma unroll
        for (int i = 0; i < 4; ++i) {
            int   row = quad * 4 + i;
            float g   = sgate[buf][row];
            ctile[buf][row * CSTRIDE + o0] = f2bf(g * (acc0[i] + be0));
            ctile[buf][row * CSTRIDE + o1] = f2bf(g * (acc1[i] + be1));
        }

        // ---- publish next tile, barrier, wide 16B store ----
        if (more) {
            if (tid < 16) { stok[buf ^ 1][tid] = nmt; sgate[buf ^ 1][tid] = nmg; }
            *(bf16x8*)&atile[buf ^ 1][r0i * TOKSTRIDE + s0i * 8] = nx0;
            if (has1) *(bf16x8*)&atile[buf ^ 1][r1i * TOKSTRIDE + s1i * 8] = nx1;
        }
        __syncthreads();

        {
            int row = tid >> 4, chk = tid & 15;
            int raw = stok[buf][row];
            int t    = raw & 0x1FFFF;
            int slot = raw >> 20;
            *(bf16x8*)(slab + (size_t)slot * SLABROWS * DOUT
                            + (size_t)t * DOUT + chk * 8) =
                *(const bf16x8*)&ctile[buf][row * CSTRIDE + chk * 8];
        }
    }
    #undef FETCH_RAW
    #undef FETCH_G
}

// ---------------- K3_combine: out = slab0 + slab1 ----------------------------
__global__ __launch_bounds__(256)
void k3_combine(const unsigned short* __restrict__ slab,
                float* __restrict__ out)
{
    __shared__ float out_lds[32 * 129];

    const int tid = threadIdx.x;
    const int bid = blockIdx.x;
    const int bh  = bid >> 1;
    const int wh  = bid & 1;
    const int b   = bh >> 6;
    const int h   = bh & 63;
    const int t0  = bh * 64 + wh * 32;

    const unsigned short* s0 = slab;
    const unsigned short* s1 = slab + (size_t)SLABROWS * DOUT;

    #pragma unroll
    for (int it = 0; it < 2; ++it) {
        int idx = it * 256 + tid;          // 512 = 32 tokens x 16 chunks
        int tl = idx >> 4, chk = idx & 15;
        size_t gt = (size_t)t0 + tl;
        bf16x8 v0 = *(const bf16x8*)(s0 + gt * DOUT + chk * 8);
        bf16x8 v1 = *(const bf16x8*)(s1 + gt * DOUT + chk * 8);
        float* dst = &out_lds[tl * 129 + chk * 8];
        #pragma unroll
        for (int q = 0; q < 8; ++q)
            dst[q] = bf2f((unsigned short)v0[q]) + bf2f((unsigned short)v1[q]);
    }
    __syncthreads();

    // float4 transposed store: 1024 float4 = 128 o-rows x 8 groups of 4 w
    float* outp = out + ((size_t)b * DOUT) * 4096 + h * 64 + wh * 32;
    for (int idx = tid; idx < 1024; idx += 256) {
        int o = idx >> 3, wg = (idx & 7) * 4;
        float4 v;
        v.x = out_lds[(wg + 0) * 129 + o];
        v.y = out_lds[(wg + 1) * 129 + o];
        v.z = out_lds[(wg + 2) * 129 + o];
        v.w = out_lds[(wg + 3) * 129 + o];
        *(float4*)(outp + (size_t)o * 4096 + wg) = v;
    }
}

// ================== fallback (round-3 fused path, needs only 442 KB ws) ======
#define OUTSTRIDE 129
#define MAXROWS 320
#define MAXTILES 20

__global__ __launch_bounds__(256)
void moe_conv2d_mfma(const float* __restrict__ x,
                     const float* __restrict__ conv_w,
                     const float* __restrict__ router_w,
                     const unsigned short* __restrict__ wt,
                     const float* __restrict__ b_experts,
                     const float* __restrict__ b_shared,
                     float* __restrict__ out)
{
    __shared__ __attribute__((aligned(16))) unsigned short tokbf[64 * TOKSTRIDE];
    __shared__ float out_lds[64 * OUTSTRIDE];
    __shared__ float rw[DIN * NEXP];
    __shared__ float logits[64 * LOGSTRIDE];
    __shared__ float sg0[64], sg1[64];
    __shared__ int   se0[64], se1[64];
    __shared__ int   rowtok[MAXROWS];
    __shared__ float rowgate[MAXROWS];
    __shared__ int   cbuf[NMAT];
    __shared__ int   tilexp[MAXTILES], tilebase[MAXTILES];
    __shared__ int   ntiles_s;

    const int tid = threadIdx.x;
    const int bh  = blockIdx.x;
    const int b   = bh >> 6;
    const int h   = bh & 63;

    for (int idx = tid; idx < DIN * NEXP; idx += 256) rw[idx] = router_w[idx];
    for (int idx = tid; idx < 64 * LOGSTRIDE; idx += 256) logits[idx] = 0.f;
    __syncthreads();
    {
        const int w  = tid & 63;
        const int fq = tid >> 6;
        float lacc[8];
        #pragma unroll
        for (int e = 0; e < 8; ++e) lacc[e] = 0.f;
        for (int i = 0; i < 48; ++i) {
            int f = i * 4 + fq;
            int c = f / 3;
            const float* wp    = conv_w + f * 9;
            const float* xbase = x + ((size_t)(b * 64 + c) * 64) * 64;
            float acc = 0.f;
            #pragma unroll
            for (int kh = 0; kh < 3; ++kh) {
                int hh = h + kh - 1;
                if (hh < 0 || hh > 63) continue;
                const float* xrow = xbase + hh * 64;
                #pragma unroll
                for (int kw = 0; kw < 3; ++kw) {
                    int ww = w + kw - 1;
                    if (ww < 0 || ww > 63) continue;
                    acc += xrow[ww] * wp[kh * 3 + kw];
                }
            }
            tokbf[w * TOKSTRIDE + f] = f2bf(acc);
            const float* rwf = rw + f * 8;
            #pragma unroll
            for (int e = 0; e < 8; ++e) lacc[e] += acc * rwf[e];
        }
        #pragma unroll
        for (int e = 0; e < 8; ++e)
            atomicAdd(&logits[w * LOGSTRIDE + e], lacc[e]);
    }
    __syncthreads();
    if (tid < 64) {
        int w = tid;
        float l[8];
        #pragma unroll
        for (int e = 0; e < 8; ++e) l[e] = logits[w * LOGSTRIDE + e];
        int e0 = 0; float l0 = l[0];
        #pragma unroll
        for (int e = 1; e < 8; ++e) if (l[e] > l0) { l0 = l[e]; e0 = e; }
        int e1 = -1; float l1 = -INFINITY;
        #pragma unroll
        for (int e = 0; e < 8; ++e) {
            if (e == e0) continue;
            if (l[e] > l1) { l1 = l[e]; e1 = e; }
        }
        float g0 = 1.f / (1.f + expf(l1 - l0));
        sg0[w] = g0; sg1[w] = 1.f - g0;
        se0[w] = e0; se1[w] = e1;
    }
    __syncthreads();
    for (int idx = tid; idx < 64 * DOUT; idx += 256) {
        int t = idx >> 7, o = idx & 127;
        out_lds[t * OUTSTRIDE + o] = b_shared[o]
            + sg0[t] * b_experts[se0[t] * DOUT + o]
            + sg1[t] * b_experts[se1[t] * DOUT + o];
    }
    if (tid < 8) {
        int c = 0;
        for (int t = 0; t < 64; ++t) c += (se0[t] == tid) + (se1[t] == tid);
        cbuf[tid] = c;
    } else if (tid == 8) cbuf[8] = 64;
    __syncthreads();
    if (tid < NMAT) {
        int e = tid;
        int start = 0, tb = 0;
        for (int e2 = 0; e2 < e; ++e2) {
            int ce = cbuf[e2];
            int tl = (ce + 15) >> 4;
            start += tl << 4; tb += tl;
        }
        int ce = cbuf[e];
        int tl = (ce + 15) >> 4;
        for (int j = 0; j < tl; ++j) { tilexp[tb + j] = e; tilebase[tb + j] = start + (j << 4); }
        if (e == 8) ntiles_s = tb + tl;
        int j = 0;
        if (e < 8) {
            for (int t = 0; t < 64; ++t) {
                if (se0[t] == e) { rowtok[start + j] = t; rowgate[start + j] = sg0[t]; ++j; }
                if (se1[t] == e) { rowtok[start + j] = t; rowgate[start + j] = sg1[t]; ++j; }
            }
        } else {
            for (int t = 0; t < 64; ++t) { rowtok[start + j] = t; rowgate[start + j] = 1.f; ++j; }
        }
        for (; j < (tl << 4); ++j) { rowtok[start + j] = 0; rowgate[start + j] = 0.f; }
    }
    __syncthreads();
    {
        const int wave = tid >> 6;
        const int lane = tid & 63;
        const int m16  = lane & 15;
        const int quad = lane >> 4;
        const int nt   = ntiles_s;
        for (int ti = wave; ti < nt; ti += 4) {
            int e    = tilexp[ti];
            int base = tilebase[ti];
            int tA = rowtok[base + m16];
            bf16x8 a[6];
            #pragma unroll
            for (int ks = 0; ks < 6; ++ks)
                a[ks] = *(const bf16x8*)(tokbf + tA * TOKSTRIDE + ks * 32 + quad * 8);
            int st[4]; float sgt[4];
            #pragma unroll
            for (int i2 = 0; i2 < 4; ++i2) {
                int r = base + quad * 4 + i2;
                st[i2] = rowtok[r]; sgt[i2] = rowgate[r];
            }
            const unsigned short* we = wt + (size_t)e * DOUT * DIN;
            for (int n = 0; n < 8; ++n) {
                const unsigned short* wp = we + (size_t)(n * 16 + m16) * DIN + quad * 8;
                f32x4 acc = {0.f, 0.f, 0.f, 0.f};
                #pragma unroll
                for (int ks = 0; ks < 6; ++ks) {
                    bf16x8 bfr2 = *(const bf16x8*)(wp + ks * 32);
                    acc = __builtin_amdgcn_mfma_f32_16x16x32_bf16(a[ks], bfr2, acc, 0, 0, 0);
                }
                int ncol = n * 16 + m16;
                #pragma unroll
                for (int i2 = 0; i2 < 4; ++i2)
                    atomicAdd(&out_lds[st[i2] * OUTSTRIDE + ncol], sgt[i2] * acc[i2]);
            }
        }
    }
    __syncthreads();
    {
        float* outp = out + (((size_t)b * DOUT) * 64 + h) * 64;
        for (int idx = tid; idx < 64 * DOUT; idx += 256) {
            int w = idx & 63, o = idx >> 6;
            outp[(size_t)o * 4096 + w] = out_lds[w * OUTSTRIDE + o];
        }
    }
}

__global__ __launch_bounds__(256)
void prep_weights_only(const float* __restrict__ w_experts,
                       const float* __restrict__ w_shared,
                       unsigned short* __restrict__ wt)
{
    int e = blockIdx.x;
    const float* src = (e < 8) ? (w_experts + (size_t)e * DIN * DOUT) : w_shared;
    unsigned short* dst = wt + (size_t)e * DOUT * DIN;
    for (int idx = threadIdx.x; idx < DOUT * DIN; idx += 256) {
        int n = idx / DIN, k = idx - n * DIN;
        dst[idx] = f2bf(src[k * DOUT + n]);
    }
}

// =============================================================================
extern "C" void kernel_launch(void* const* d_in, const int* in_sizes, int n_in,
                              void* d_out, int out_size, void* d_ws, size_t ws_size,
                              hipStream_t stream)
{
    const float* x         = (const float*)d_in[0];
    const float* conv_w    = (const float*)d_in[1];
    const float* router_w  = (const float*)d_in[2];
    const float* w_experts = (const float*)d_in[3];
    const float* b_experts = (const float*)d_in[4];
    const float* w_shared  = (const float*)d_in[5];
    const float* b_shared  = (const float*)d_in[6];
    float* out = (float*)d_out;
    char* ws = (char*)d_ws;

    if (ws_size >= WS_TOTAL) {
        unsigned short* tokbuf  = (unsigned short*)(ws + WS_TOK);
        unsigned short* wt      = (unsigned short*)(ws + WS_WT);
        int*            cnt     = (int*)(ws + WS_CNT);
        int*            rowtok  = (int*)(ws + WS_RT);
        float*          rowgate = (float*)(ws + WS_RG);
        unsigned short* slab    = (unsigned short*)(ws + WS_SLAB);

        hipMemsetAsync(cnt, 0, 16 * sizeof(int), stream);   // graph memset node
        k1a_conv<<<dim3(1024), dim3(256), 0, stream>>>(
            x, conv_w, router_w, w_experts, w_shared,
            tokbuf, wt, cnt, rowtok, rowgate);
        k4_all<<<dim3(1024), dim3(256), 0, stream>>>(
            tokbuf, wt, b_experts, b_shared, cnt, rowtok, rowgate, slab);
        k3_combine<<<dim3(2048), dim3(256), 0, stream>>>(slab, out);
    } else {
        // fallback: round-3 fused path (needs only 442 KB ws)
        unsigned short* wt = (unsigned short*)ws;
        prep_weights_only<<<dim3(NMAT), dim3(256), 0, stream>>>(w_experts, w_shared, wt);
        moe_conv2d_mfma<<<dim3(1024), dim3(256), 0, stream>>>(
            x, conv_w, router_w, wt, b_experts, b_shared, out);
    }
}